// Round 1
// baseline (1079.450 us; speedup 1.0000x reference)
//
#include <hip/hip_runtime.h>
#include <math.h>

// Problem constants (AVWGCN): B=64, N=2048, C_IN=C_OUT=64, CHEB_K=3, EMBED=16
#define NN    2048          // nodes
#define BATCH 64
#define CIN   64
#define COUT  64
#define EMB   16
#define JDIM  (BATCH * CIN) // 4096 columns of the propagation GEMMs

// ---------------------------------------------------------------------------
// x (B,N,C) -> Xt (N, B*C)   [node-major layout for GEMM + final kernel]
// ---------------------------------------------------------------------------
__global__ __launch_bounds__(256) void transpose_x_kernel(
    const float* __restrict__ x, float* __restrict__ Xt) {
    int idx = blockIdx.x * 256 + threadIdx.x;          // over N*B*(C/4) float4s
    const int total = NN * BATCH * (CIN / 4);
    if (idx >= total) return;
    int c4 = idx % (CIN / 4);
    int b  = (idx / (CIN / 4)) % BATCH;
    int n  = idx / ((CIN / 4) * BATCH);
    const float4* src = reinterpret_cast<const float4*>(x) +
                        ((size_t)(b * NN + n) * (CIN / 4) + c4);
    float4* dst = reinterpret_cast<float4*>(Xt) +
                  ((size_t)(n * BATCH + b) * (CIN / 4) + c4);
    *dst = *src;
}

// ---------------------------------------------------------------------------
// S[n,:] = softmax(relu(E[n] @ E^T))   one block per row
// ---------------------------------------------------------------------------
__global__ __launch_bounds__(256) void support_kernel(
    const float* __restrict__ E, float* __restrict__ S) {
    const int n   = blockIdx.x;
    const int tid = threadIdx.x;
    __shared__ float vals[NN];       // 8 KB
    __shared__ float red[4];

    float en[EMB];
#pragma unroll
    for (int d = 0; d < EMB; ++d) en[d] = E[n * EMB + d];

    float lmax = -1e30f;
    for (int m = tid; m < NN; m += 256) {
        const float4* em = reinterpret_cast<const float4*>(E + m * EMB);
        float dot = 0.f;
#pragma unroll
        for (int q = 0; q < EMB / 4; ++q) {
            float4 v = em[q];
            dot += en[q*4+0]*v.x + en[q*4+1]*v.y + en[q*4+2]*v.z + en[q*4+3]*v.w;
        }
        float r = fmaxf(dot, 0.f);   // relu
        vals[m] = r;
        lmax = fmaxf(lmax, r);
    }
#pragma unroll
    for (int off = 32; off > 0; off >>= 1)
        lmax = fmaxf(lmax, __shfl_down(lmax, off, 64));
    if ((tid & 63) == 0) red[tid >> 6] = lmax;
    __syncthreads();
    const float gmax = fmaxf(fmaxf(red[0], red[1]), fmaxf(red[2], red[3]));
    __syncthreads();

    float lsum = 0.f;
    for (int m = tid; m < NN; m += 256) {
        float e = expf(vals[m] - gmax);
        vals[m] = e;
        lsum += e;
    }
#pragma unroll
    for (int off = 32; off > 0; off >>= 1)
        lsum += __shfl_down(lsum, off, 64);
    if ((tid & 63) == 0) red[tid >> 6] = lsum;
    __syncthreads();
    const float inv = 1.f / (red[0] + red[1] + red[2] + red[3]);

    for (int m = tid; m < NN; m += 256)
        S[(size_t)n * NN + m] = vals[m] * inv;
}

// ---------------------------------------------------------------------------
// C(2048x4096) = A(2048x2048) @ B(2048x4096); mode==1: C = 2*A@B - Xsub
// Tile: 128x128x16, 256 threads, 8x8 micro-tile per thread.
// ---------------------------------------------------------------------------
#define BM 128
#define BJ 128
#define BK 16
__global__ __launch_bounds__(256) void sgemm_kernel(
    const float* __restrict__ A, const float* __restrict__ B,
    const float* __restrict__ Xsub, float* __restrict__ C, int mode) {
    const int tid    = threadIdx.x;
    const int rowBlk = blockIdx.y * BM;
    const int colBlk = blockIdx.x * BJ;
    const int K = NN;

    __shared__ float As[BK][BM + 4];   // transposed A-tile: As[k][m]
    __shared__ float Bs[BK][BJ + 4];

    float acc[8][8] = {};
    const int tm = tid >> 4;   // 0..15 -> output rows tm*8..+7
    const int tj = tid & 15;   // 0..15 -> output cols tj*8..+7

    for (int k0 = 0; k0 < K; k0 += BK) {
        // A tile: 128 rows x 16 k, store transposed
#pragma unroll
        for (int i = 0; i < 2; ++i) {
            int f  = tid + i * 256;          // 0..511 float4 slots
            int m  = f >> 2;
            int kq = (f & 3) * 4;
            float4 v = *reinterpret_cast<const float4*>(
                A + (size_t)(rowBlk + m) * K + k0 + kq);
            As[kq + 0][m] = v.x; As[kq + 1][m] = v.y;
            As[kq + 2][m] = v.z; As[kq + 3][m] = v.w;
        }
        // B tile: 16 k-rows x 128 cols
#pragma unroll
        for (int i = 0; i < 2; ++i) {
            int f  = tid + i * 256;
            int kr = f >> 5;
            int jq = (f & 31) * 4;
            *reinterpret_cast<float4*>(&Bs[kr][jq]) =
                *reinterpret_cast<const float4*>(
                    B + (size_t)(k0 + kr) * JDIM + colBlk + jq);
        }
        __syncthreads();
#pragma unroll
        for (int kk = 0; kk < BK; ++kk) {
            float a[8], b[8];
            *reinterpret_cast<float4*>(&a[0]) = *reinterpret_cast<float4*>(&As[kk][tm * 8]);
            *reinterpret_cast<float4*>(&a[4]) = *reinterpret_cast<float4*>(&As[kk][tm * 8 + 4]);
            *reinterpret_cast<float4*>(&b[0]) = *reinterpret_cast<float4*>(&Bs[kk][tj * 8]);
            *reinterpret_cast<float4*>(&b[4]) = *reinterpret_cast<float4*>(&Bs[kk][tj * 8 + 4]);
#pragma unroll
            for (int r = 0; r < 8; ++r)
#pragma unroll
                for (int c = 0; c < 8; ++c)
                    acc[r][c] += a[r] * b[c];
        }
        __syncthreads();
    }

#pragma unroll
    for (int r = 0; r < 8; ++r) {
        size_t base = (size_t)(rowBlk + tm * 8 + r) * JDIM + colBlk + tj * 8;
        if (mode == 0) {
            *reinterpret_cast<float4*>(C + base) =
                make_float4(acc[r][0], acc[r][1], acc[r][2], acc[r][3]);
            *reinterpret_cast<float4*>(C + base + 4) =
                make_float4(acc[r][4], acc[r][5], acc[r][6], acc[r][7]);
        } else {
            float4 x0 = *reinterpret_cast<const float4*>(Xsub + base);
            float4 x1 = *reinterpret_cast<const float4*>(Xsub + base + 4);
            *reinterpret_cast<float4*>(C + base) =
                make_float4(2.f*acc[r][0]-x0.x, 2.f*acc[r][1]-x0.y,
                            2.f*acc[r][2]-x0.z, 2.f*acc[r][3]-x0.w);
            *reinterpret_cast<float4*>(C + base + 4) =
                make_float4(2.f*acc[r][4]-x1.x, 2.f*acc[r][5]-x1.y,
                            2.f*acc[r][6]-x1.z, 2.f*acc[r][7]-x1.w);
        }
    }
}

// ---------------------------------------------------------------------------
// Per node n: w[k,i,o] = sum_d E[n,d]*wp[d,k,i,o];  bias[o] = E[n]@bp
// out[b,n,o] = sum_{k,i} g_k[b,i] * w[k,i,o] + bias[o]
// g_0 = Xt[n], g_1 = G1[n], g_2 = G2[n]  (each 64x64, node-contiguous)
// ---------------------------------------------------------------------------
__global__ __launch_bounds__(256) void final_kernel(
    const float* __restrict__ E,  const float* __restrict__ wp,
    const float* __restrict__ bp, const float* __restrict__ Xt,
    const float* __restrict__ G1, const float* __restrict__ G2,
    float* __restrict__ out) {
    const int n   = blockIdx.x;
    const int tid = threadIdx.x;
    __shared__ float wl[3 * CIN * COUT];     // 48 KB: w[k][i][o]
    __shared__ float gl[3 * BATCH * CIN];    // 48 KB: g[k][b][i]

    float en[EMB];
#pragma unroll
    for (int d = 0; d < EMB; ++d) en[d] = E[n * EMB + d];

    // stage g tiles (3 x 4096 floats, coalesced float4)
    {
        const float4* s0 = reinterpret_cast<const float4*>(Xt + (size_t)n * JDIM);
        const float4* s1 = reinterpret_cast<const float4*>(G1 + (size_t)n * JDIM);
        const float4* s2 = reinterpret_cast<const float4*>(G2 + (size_t)n * JDIM);
        float4* g4 = reinterpret_cast<float4*>(gl);
        for (int f = tid; f < 1024; f += 256) {
            g4[f]        = s0[f];
            g4[1024 + f] = s1[f];
            g4[2048 + f] = s2[f];
        }
    }
    // generate weights: wl[e] = sum_d en[d] * wp[d*12288 + e]
    for (int e = tid; e < 3 * CIN * COUT; e += 256) {
        float a = 0.f;
#pragma unroll
        for (int d = 0; d < EMB; ++d) a += en[d] * wp[d * 12288 + e];
        wl[e] = a;
    }
    __syncthreads();

    // 4x4 micro-tile: b = bt*4..+3, o = ot*4..+3
    const int bt = tid >> 4, ot = tid & 15;
    float acc[4][4] = {};
#pragma unroll
    for (int k = 0; k < 3; ++k) {
        const float* g = gl + k * 4096;
        const float* w = wl + k * 4096;
        for (int i = 0; i < CIN; ++i) {
            float4 wv = *reinterpret_cast<const float4*>(w + i * COUT + ot * 4);
            float g0 = g[(bt * 4 + 0) * CIN + i];
            float g1 = g[(bt * 4 + 1) * CIN + i];
            float g2 = g[(bt * 4 + 2) * CIN + i];
            float g3 = g[(bt * 4 + 3) * CIN + i];
            acc[0][0] += g0 * wv.x; acc[0][1] += g0 * wv.y; acc[0][2] += g0 * wv.z; acc[0][3] += g0 * wv.w;
            acc[1][0] += g1 * wv.x; acc[1][1] += g1 * wv.y; acc[1][2] += g1 * wv.z; acc[1][3] += g1 * wv.w;
            acc[2][0] += g2 * wv.x; acc[2][1] += g2 * wv.y; acc[2][2] += g2 * wv.z; acc[2][3] += g2 * wv.w;
            acc[3][0] += g3 * wv.x; acc[3][1] += g3 * wv.y; acc[3][2] += g3 * wv.z; acc[3][3] += g3 * wv.w;
        }
    }
    // bias for this thread's 4 o's
    float bo[4];
#pragma unroll
    for (int c = 0; c < 4; ++c) {
        float s = 0.f;
#pragma unroll
        for (int d = 0; d < EMB; ++d) s += en[d] * bp[d * COUT + ot * 4 + c];
        bo[c] = s;
    }
#pragma unroll
    for (int r = 0; r < 4; ++r) {
        int b = bt * 4 + r;
        *reinterpret_cast<float4*>(out + ((size_t)b * NN + n) * COUT + ot * 4) =
            make_float4(acc[r][0] + bo[0], acc[r][1] + bo[1],
                        acc[r][2] + bo[2], acc[r][3] + bo[3]);
    }
}

// ---------------------------------------------------------------------------
extern "C" void kernel_launch(void* const* d_in, const int* in_sizes, int n_in,
                              void* d_out, int out_size, void* d_ws, size_t ws_size,
                              hipStream_t stream) {
    const float* x  = (const float*)d_in[0];   // (64,2048,64)
    const float* E  = (const float*)d_in[1];   // (2048,16)
    const float* wp = (const float*)d_in[2];   // (16,3,64,64)
    const float* bp = (const float*)d_in[3];   // (16,64)
    float* out = (float*)d_out;                // (64,2048,64)

    float* ws = (float*)d_ws;
    float* S  = ws;                                  // 2048*2048        = 16 MB
    float* Xt = S  + (size_t)NN * NN;                // 2048*4096        = 32 MB
    float* G1 = Xt + (size_t)NN * JDIM;              // 32 MB
    float* G2 = G1 + (size_t)NN * JDIM;              // 32 MB  (total 117.5 MB)

    transpose_x_kernel<<<(NN * BATCH * (CIN / 4) + 255) / 256, 256, 0, stream>>>(x, Xt);
    support_kernel<<<NN, 256, 0, stream>>>(E, S);

    dim3 ggrid(JDIM / BJ, NN / BM);                  // 32 x 16 = 512 blocks
    sgemm_kernel<<<ggrid, 256, 0, stream>>>(S, Xt, nullptr, G1, 0);  // G1 = S@Xt
    sgemm_kernel<<<ggrid, 256, 0, stream>>>(S, G1, Xt, G2, 1);       // G2 = 2*S@G1 - Xt

    final_kernel<<<NN, 256, 0, stream>>>(E, wp, bp, Xt, G1, G2, out);
}

// Round 2
// 396.152 us; speedup vs baseline: 2.7248x; 2.7248x over previous
//
#include <hip/hip_runtime.h>
#include <math.h>

// AVWGCN: B=64, N=2048, C_IN=C_OUT=64, CHEB_K=3, EMBED=16
#define NN    2048
#define BATCH 64
#define CIN   64
#define COUT  64
#define EMB   16
#define JDIM  4096   // BATCH*CIN

typedef __bf16 bf16_t;
typedef __bf16 bf16x8 __attribute__((ext_vector_type(8)));
typedef float  f32x4  __attribute__((ext_vector_type(4)));

#define GLOAD16(gp, lp) __builtin_amdgcn_global_load_lds( \
    (const __attribute__((address_space(1))) void*)(gp),  \
    (__attribute__((address_space(3))) void*)(lp), 16, 0, 0)

// ---------------------------------------------------------------------------
// x (B,N,C) fp32 -> Y0 (JDIM, NN) bf16 : Y0[b*64+c][n] = x[b][n][c]
// ---------------------------------------------------------------------------
__global__ __launch_bounds__(256) void y0_kernel(const float* __restrict__ x,
                                                 bf16_t* __restrict__ Y0) {
    __shared__ float tile[64][65];
    const int n0 = blockIdx.x * 64, b = blockIdx.y, tid = threadIdx.x;
    const int c = tid & 63, nn0 = tid >> 6;
    const float* src = x + ((size_t)b * NN + n0) * CIN + c;
#pragma unroll
    for (int p = 0; p < 16; ++p) {
        int nn = nn0 + p * 4;
        tile[nn][c] = src[(size_t)nn * CIN];
    }
    __syncthreads();
    const int cc = tid >> 2, q = tid & 3;          // row cc, n-chunk q*16
    bf16_t* dst = Y0 + (size_t)(b * 64 + cc) * NN + n0 + q * 16;
#pragma unroll
    for (int s4 = 0; s4 < 4; ++s4) {
        ushort4 pk;
        pk.x = __builtin_bit_cast(unsigned short, (bf16_t)tile[q * 16 + s4 * 4 + 0][cc]);
        pk.y = __builtin_bit_cast(unsigned short, (bf16_t)tile[q * 16 + s4 * 4 + 1][cc]);
        pk.z = __builtin_bit_cast(unsigned short, (bf16_t)tile[q * 16 + s4 * 4 + 2][cc]);
        pk.w = __builtin_bit_cast(unsigned short, (bf16_t)tile[q * 16 + s4 * 4 + 3][cc]);
        *reinterpret_cast<ushort4*>(dst + s4 * 4) = pk;
    }
}

// ---------------------------------------------------------------------------
// Sb[n,:] = softmax(relu(E[n] @ E^T)) as bf16, one block per row
// ---------------------------------------------------------------------------
__global__ __launch_bounds__(256) void support_kernel(
    const float* __restrict__ E, bf16_t* __restrict__ Sb) {
    const int n = blockIdx.x, tid = threadIdx.x;
    __shared__ float vals[NN];
    __shared__ float red[4];

    float en[EMB];
#pragma unroll
    for (int d = 0; d < EMB; ++d) en[d] = E[n * EMB + d];

    float lmax = -1e30f;
    for (int m = tid; m < NN; m += 256) {
        const float4* em = reinterpret_cast<const float4*>(E + m * EMB);
        float dot = 0.f;
#pragma unroll
        for (int q = 0; q < EMB / 4; ++q) {
            float4 v = em[q];
            dot += en[q*4+0]*v.x + en[q*4+1]*v.y + en[q*4+2]*v.z + en[q*4+3]*v.w;
        }
        float r = fmaxf(dot, 0.f);
        vals[m] = r;
        lmax = fmaxf(lmax, r);
    }
#pragma unroll
    for (int off = 32; off > 0; off >>= 1)
        lmax = fmaxf(lmax, __shfl_down(lmax, off, 64));
    if ((tid & 63) == 0) red[tid >> 6] = lmax;
    __syncthreads();
    const float gmax = fmaxf(fmaxf(red[0], red[1]), fmaxf(red[2], red[3]));
    __syncthreads();

    float lsum = 0.f;
    for (int m = tid; m < NN; m += 256) {
        float e = expf(vals[m] - gmax);
        vals[m] = e;
        lsum += e;
    }
#pragma unroll
    for (int off = 32; off > 0; off >>= 1)
        lsum += __shfl_down(lsum, off, 64);
    if ((tid & 63) == 0) red[tid >> 6] = lsum;
    __syncthreads();
    const float inv = 1.f / (red[0] + red[1] + red[2] + red[3]);

    for (int m = tid; m < NN; m += 256)
        Sb[(size_t)n * NN + m] = (bf16_t)(vals[m] * inv);
}

// ---------------------------------------------------------------------------
// C (4096 x 2048) = A (4096 x 2048) @ Bt^T, both K(node)-contiguous bf16.
// MODE 0: C = A@Bt^T        (Y1 = Y0 @ S^T)
// MODE 1: C = 2*A@Bt^T - Y0 (Y2)
// m97 structure: 128x128 tile, BK=32, 4 waves (2x2), global_load_lds w=16,
// mfma_f32_16x16x32_bf16, 4x4 fragments/wave.
// ---------------------------------------------------------------------------
template<int MODE>
__global__ __launch_bounds__(256) void gemm_bt(
    const bf16_t* __restrict__ A, const bf16_t* __restrict__ Bt,
    const bf16_t* __restrict__ Y0, bf16_t* __restrict__ C) {
    __shared__ bf16_t As[128 * 32];
    __shared__ bf16_t Bs[128 * 32];
    const int tid  = threadIdx.x;
    const int wave = tid >> 6, lane = tid & 63;
    const int pBlk = blockIdx.x * 128;    // node cols
    const int mBlk = blockIdx.y * 128;    // j rows
    const int K = NN;

    // staging: wave w covers rows [w*32, w*32+32); 2 issues of 16 rows each.
    // lane -> row (lane>>2), k-quad (lane&3)*8  (16B contiguous global)
    const bf16_t* aSrc = A  + (size_t)(mBlk + wave * 32 + (lane >> 2)) * K + (lane & 3) * 8;
    const bf16_t* bSrc = Bt + (size_t)(pBlk + wave * 32 + (lane >> 2)) * K + (lane & 3) * 8;
    bf16_t* aDst = As + wave * 1024;      // elems; wave region = 32 rows * 32
    bf16_t* bDst = Bs + wave * 1024;

    f32x4 acc[4][4] = {};
    const int wr = wave >> 1, wc = wave & 1;
    const int lrow = lane & 15, lk = (lane >> 4) * 8;

    for (int k0 = 0; k0 < K; k0 += 32) {
        GLOAD16(aSrc + k0,                   aDst);
        GLOAD16(aSrc + k0 + (size_t)16 * K,  aDst + 512);
        GLOAD16(bSrc + k0,                   bDst);
        GLOAD16(bSrc + k0 + (size_t)16 * K,  bDst + 512);
        __syncthreads();   // compiler drains vmcnt before barrier

        bf16x8 af[4], bb[4];
#pragma unroll
        for (int mf = 0; mf < 4; ++mf)
            af[mf] = *reinterpret_cast<const bf16x8*>(
                &As[(wr * 64 + mf * 16 + lrow) * 32 + lk]);
#pragma unroll
        for (int nf = 0; nf < 4; ++nf)
            bb[nf] = *reinterpret_cast<const bf16x8*>(
                &Bs[(wc * 64 + nf * 16 + lrow) * 32 + lk]);
#pragma unroll
        for (int mf = 0; mf < 4; ++mf)
#pragma unroll
            for (int nf = 0; nf < 4; ++nf)
                acc[mf][nf] = __builtin_amdgcn_mfma_f32_16x16x32_bf16(
                    af[mf], bb[nf], acc[mf][nf], 0, 0, 0);
        __syncthreads();
    }

    // C/D layout: col = lane&15, row = (lane>>4)*4 + r   [m89-verified]
    const int orow = (lane >> 4) * 4, ocol = lane & 15;
#pragma unroll
    for (int mf = 0; mf < 4; ++mf)
#pragma unroll
        for (int nf = 0; nf < 4; ++nf)
#pragma unroll
            for (int r = 0; r < 4; ++r) {
                size_t row = (size_t)(mBlk + wr * 64 + mf * 16 + orow + r);
                size_t col = (size_t)(pBlk + wc * 64 + nf * 16 + ocol);
                float v = acc[mf][nf][r];
                if (MODE == 1) v = 2.f * v - (float)Y0[row * NN + col];
                C[row * NN + col] = (bf16_t)v;
            }
}

// ---------------------------------------------------------------------------
// Per node n: weights from wp (fp32, exact), g0 from x (fp32),
// g1/g2 column-gathered from Y1/Y2 (bf16). out[b][n][o].
// ---------------------------------------------------------------------------
__global__ __launch_bounds__(256) void final_kernel(
    const float* __restrict__ x,  const float* __restrict__ E,
    const float* __restrict__ wp, const float* __restrict__ bp,
    const bf16_t* __restrict__ Y1, const bf16_t* __restrict__ Y2,
    float* __restrict__ out) {
    const int n = blockIdx.x, tid = threadIdx.x;
    __shared__ float  wl[3 * 4096];    // 48 KB  w[k][i][o]
    __shared__ float  g0[4096];        // 16 KB  g0[b*64+i]
    __shared__ bf16_t g12[2 * 4096];   // 16 KB  g1,g2

    float en[EMB];
#pragma unroll
    for (int d = 0; d < EMB; ++d) en[d] = E[n * EMB + d];

    for (int f = tid; f < 1024; f += 256) {
        int b = f >> 4, c4 = f & 15;
        *reinterpret_cast<float4*>(&g0[b * 64 + c4 * 4]) =
            *reinterpret_cast<const float4*>(x + ((size_t)b * NN + n) * CIN + c4 * 4);
    }
    for (int j = tid; j < JDIM; j += 256) {
        g12[j]        = Y1[(size_t)j * NN + n];
        g12[JDIM + j] = Y2[(size_t)j * NN + n];
    }
    for (int e = tid; e < 3 * CIN * COUT; e += 256) {
        float a = 0.f;
#pragma unroll
        for (int d = 0; d < EMB; ++d) a += en[d] * wp[d * 12288 + e];
        wl[e] = a;
    }
    __syncthreads();

    const int bt = tid >> 4, ot = tid & 15;
    float acc[4][4] = {};
#pragma unroll
    for (int k = 0; k < 3; ++k) {
        const float* w = wl + k * 4096;
        for (int i = 0; i < CIN; ++i) {
            float4 wv = *reinterpret_cast<const float4*>(w + i * COUT + ot * 4);
            float gr[4];
#pragma unroll
            for (int r = 0; r < 4; ++r) {
                int j = (bt * 4 + r) * CIN + i;
                gr[r] = (k == 0) ? g0[j] : (float)g12[(k - 1) * 4096 + j];
            }
#pragma unroll
            for (int r = 0; r < 4; ++r) {
                acc[r][0] += gr[r] * wv.x; acc[r][1] += gr[r] * wv.y;
                acc[r][2] += gr[r] * wv.z; acc[r][3] += gr[r] * wv.w;
            }
        }
    }
    float bo[4];
#pragma unroll
    for (int c = 0; c < 4; ++c) {
        float s = 0.f;
#pragma unroll
        for (int d = 0; d < EMB; ++d) s += en[d] * bp[d * COUT + ot * 4 + c];
        bo[c] = s;
    }
#pragma unroll
    for (int r = 0; r < 4; ++r) {
        int b = bt * 4 + r;
        *reinterpret_cast<float4*>(out + ((size_t)b * NN + n) * COUT + ot * 4) =
            make_float4(acc[r][0] + bo[0], acc[r][1] + bo[1],
                        acc[r][2] + bo[2], acc[r][3] + bo[3]);
    }
}

// ---------------------------------------------------------------------------
extern "C" void kernel_launch(void* const* d_in, const int* in_sizes, int n_in,
                              void* d_out, int out_size, void* d_ws, size_t ws_size,
                              hipStream_t stream) {
    const float* x  = (const float*)d_in[0];   // (64,2048,64)
    const float* E  = (const float*)d_in[1];   // (2048,16)
    const float* wp = (const float*)d_in[2];   // (16,3,64,64)
    const float* bp = (const float*)d_in[3];   // (16,64)
    float* out = (float*)d_out;

    bf16_t* ws = (bf16_t*)d_ws;
    bf16_t* Sb = ws;                           // 2048*2048 bf16 =  8 MB
    bf16_t* Y0 = Sb + (size_t)NN * NN;         // 4096*2048 bf16 = 16 MB
    bf16_t* Y1 = Y0 + (size_t)JDIM * NN;       // 16 MB
    bf16_t* Y2 = Y1 + (size_t)JDIM * NN;       // 16 MB (total 56 MB)

    y0_kernel<<<dim3(NN / 64, BATCH), 256, 0, stream>>>(x, Y0);
    support_kernel<<<NN, 256, 0, stream>>>(E, Sb);

    dim3 ggrid(NN / 128, JDIM / 128);          // 16 x 32 = 512 blocks
    gemm_bt<0><<<ggrid, 256, 0, stream>>>(Y0, Sb, nullptr, Y1);  // Y1 = Y0@S^T
    gemm_bt<1><<<ggrid, 256, 0, stream>>>(Y1, Sb, Y0, Y2);       // Y2 = 2*Y1@S^T - Y0

    final_kernel<<<NN, 256, 0, stream>>>(x, E, wp, bp, Y1, Y2, out);
}

// Round 3
// 274.934 us; speedup vs baseline: 3.9262x; 1.4409x over previous
//
#include <hip/hip_runtime.h>
#include <math.h>

// AVWGCN: B=64, N=2048, C_IN=C_OUT=64, CHEB_K=3, EMBED=16
#define NN    2048
#define BATCH 64
#define CIN   64
#define COUT  64
#define EMB   16
#define JDIM  4096   // BATCH*CIN
#define WKI   192    // CHEB_K*CIN

typedef __bf16 bf16_t;
typedef __bf16 bf16x8 __attribute__((ext_vector_type(8)));
typedef float  f32x4  __attribute__((ext_vector_type(4)));

#define GLOAD16(gp, lp) __builtin_amdgcn_global_load_lds( \
    (const __attribute__((address_space(1))) void*)(gp),  \
    (__attribute__((address_space(3))) void*)(lp), 16, 0, 0)

static __device__ __forceinline__ unsigned short bfbits(float f) {
    return __builtin_bit_cast(unsigned short, (bf16_t)f);
}

// ---------------------------------------------------------------------------
// Wt[n][o][ki] = sum_d E[n,d] * wp[d][k][i][o], bf16.  oki = o*192 + k*64 + i.
// wp index for (d, oki): (d*192 + oki%192)*64 + oki/192.
// Block: oki-slice of 512 (2/thread, held in regs), n-chunk of 128.
// ---------------------------------------------------------------------------
__global__ __launch_bounds__(256) void wgen_kernel(
    const float* __restrict__ E, const float* __restrict__ wp,
    bf16_t* __restrict__ Wt) {
    const int R  = blockIdx.x * 512;
    const int n0 = blockIdx.y * 128;
    const int t  = threadIdx.x;
    const int oki0 = R + 2 * t;
    float w0[EMB], w1[EMB];
    {
        const int o0 = oki0 / WKI, r0 = oki0 % WKI;
        const int o1 = (oki0 + 1) / WKI, r1 = (oki0 + 1) % WKI;
#pragma unroll
        for (int d = 0; d < EMB; ++d) {
            w0[d] = wp[(size_t)(d * WKI + r0) * 64 + o0];
            w1[d] = wp[(size_t)(d * WKI + r1) * 64 + o1];
        }
    }
    for (int nn = 0; nn < 128; ++nn) {
        const int n = n0 + nn;
        const float4* e4 = reinterpret_cast<const float4*>(E + (size_t)n * EMB);
        float a0 = 0.f, a1 = 0.f;
#pragma unroll
        for (int q = 0; q < 4; ++q) {
            float4 ev = e4[q];
            a0 += ev.x*w0[q*4+0] + ev.y*w0[q*4+1] + ev.z*w0[q*4+2] + ev.w*w0[q*4+3];
            a1 += ev.x*w1[q*4+0] + ev.y*w1[q*4+1] + ev.z*w1[q*4+2] + ev.w*w1[q*4+3];
        }
        unsigned int pk = (unsigned int)bfbits(a0) | ((unsigned int)bfbits(a1) << 16);
        *reinterpret_cast<unsigned int*>(Wt + (size_t)n * 12288 + oki0) = pk;
    }
}

// ---------------------------------------------------------------------------
// x (B,N,C) fp32 -> Y0 (JDIM, NN) bf16 : Y0[b*64+c][n] = x[b][n][c]
// ---------------------------------------------------------------------------
__global__ __launch_bounds__(256) void y0_kernel(const float* __restrict__ x,
                                                 bf16_t* __restrict__ Y0) {
    __shared__ float tile[64][65];
    const int n0 = blockIdx.x * 64, b = blockIdx.y, tid = threadIdx.x;
    const int c = tid & 63, nn0 = tid >> 6;
    const float* src = x + ((size_t)b * NN + n0) * CIN + c;
#pragma unroll
    for (int p = 0; p < 16; ++p) {
        int nn = nn0 + p * 4;
        tile[nn][c] = src[(size_t)nn * CIN];
    }
    __syncthreads();
    const int cc = tid >> 2, q = tid & 3;
    bf16_t* dst = Y0 + (size_t)(b * 64 + cc) * NN + n0 + q * 16;
#pragma unroll
    for (int s4 = 0; s4 < 4; ++s4) {
        ushort4 pk;
        pk.x = bfbits(tile[q * 16 + s4 * 4 + 0][cc]);
        pk.y = bfbits(tile[q * 16 + s4 * 4 + 1][cc]);
        pk.z = bfbits(tile[q * 16 + s4 * 4 + 2][cc]);
        pk.w = bfbits(tile[q * 16 + s4 * 4 + 3][cc]);
        *reinterpret_cast<ushort4*>(dst + s4 * 4) = pk;
    }
}

// ---------------------------------------------------------------------------
// Sb[n,:] = softmax(relu(E[n] @ E^T)) as bf16, one block per row
// ---------------------------------------------------------------------------
__global__ __launch_bounds__(256) void support_kernel(
    const float* __restrict__ E, bf16_t* __restrict__ Sb) {
    const int n = blockIdx.x, tid = threadIdx.x;
    __shared__ float vals[NN];
    __shared__ float red[4];

    float en[EMB];
#pragma unroll
    for (int d = 0; d < EMB; ++d) en[d] = E[n * EMB + d];

    float lmax = -1e30f;
    for (int m = tid; m < NN; m += 256) {
        const float4* em = reinterpret_cast<const float4*>(E + m * EMB);
        float dot = 0.f;
#pragma unroll
        for (int q = 0; q < EMB / 4; ++q) {
            float4 v = em[q];
            dot += en[q*4+0]*v.x + en[q*4+1]*v.y + en[q*4+2]*v.z + en[q*4+3]*v.w;
        }
        float r = fmaxf(dot, 0.f);
        vals[m] = r;
        lmax = fmaxf(lmax, r);
    }
#pragma unroll
    for (int off = 32; off > 0; off >>= 1)
        lmax = fmaxf(lmax, __shfl_down(lmax, off, 64));
    if ((tid & 63) == 0) red[tid >> 6] = lmax;
    __syncthreads();
    const float gmax = fmaxf(fmaxf(red[0], red[1]), fmaxf(red[2], red[3]));
    __syncthreads();

    float lsum = 0.f;
    for (int m = tid; m < NN; m += 256) {
        float e = expf(vals[m] - gmax);
        vals[m] = e;
        lsum += e;
    }
#pragma unroll
    for (int off = 32; off > 0; off >>= 1)
        lsum += __shfl_down(lsum, off, 64);
    if ((tid & 63) == 0) red[tid >> 6] = lsum;
    __syncthreads();
    const float inv = 1.f / (red[0] + red[1] + red[2] + red[3]);

    for (int m = tid; m < NN; m += 256)
        Sb[(size_t)n * NN + m] = (bf16_t)(vals[m] * inv);
}

// ---------------------------------------------------------------------------
// C(4096x2048) = A @ Bt^T (both K=node contiguous, bf16).
// MODE 0: writes Cj (j-major, scale 1) AND GT (node-major, scale 1)
// MODE 1: writes only GT (node-major, scale 2)    [the -Y0 term is folded
//         into gconv as g2 = G2raw - g0 with exact fp32 x]
// ---------------------------------------------------------------------------
template<int MODE>
__global__ __launch_bounds__(256) void gemm_bt(
    const bf16_t* __restrict__ A, const bf16_t* __restrict__ Bt,
    bf16_t* __restrict__ Cj, bf16_t* __restrict__ GT) {
    __shared__ bf16_t smem[128 * 136];    // 34.8 KB; union of {As,Bs} and T
    bf16_t* As = smem;                    // 128*32
    bf16_t* Bs = smem + 4096;             // 128*32
    bf16_t* T  = smem;                    // 128*136 (epilogue reuse)
    const int tid  = threadIdx.x;
    const int wave = tid >> 6, lane = tid & 63;
    const int pBlk = blockIdx.x * 128;    // node cols
    const int mBlk = blockIdx.y * 128;    // j rows
    const int K = NN;

    const bf16_t* aSrc = A  + (size_t)(mBlk + wave * 32 + (lane >> 2)) * K + (lane & 3) * 8;
    const bf16_t* bSrc = Bt + (size_t)(pBlk + wave * 32 + (lane >> 2)) * K + (lane & 3) * 8;
    bf16_t* aDst = As + wave * 1024;
    bf16_t* bDst = Bs + wave * 1024;

    f32x4 acc[4][4] = {};
    const int wr = wave >> 1, wc = wave & 1;
    const int lrow = lane & 15, lk = (lane >> 4) * 8;

    for (int k0 = 0; k0 < K; k0 += 32) {
        GLOAD16(aSrc + k0,                  aDst);
        GLOAD16(aSrc + k0 + (size_t)16 * K, aDst + 512);
        GLOAD16(bSrc + k0,                  bDst);
        GLOAD16(bSrc + k0 + (size_t)16 * K, bDst + 512);
        __syncthreads();

        bf16x8 af[4], bb[4];
#pragma unroll
        for (int mf = 0; mf < 4; ++mf)
            af[mf] = *reinterpret_cast<const bf16x8*>(
                &As[(wr * 64 + mf * 16 + lrow) * 32 + lk]);
#pragma unroll
        for (int nf = 0; nf < 4; ++nf)
            bb[nf] = *reinterpret_cast<const bf16x8*>(
                &Bs[(wc * 64 + nf * 16 + lrow) * 32 + lk]);
#pragma unroll
        for (int mf = 0; mf < 4; ++mf)
#pragma unroll
            for (int nf = 0; nf < 4; ++nf)
                acc[mf][nf] = __builtin_amdgcn_mfma_f32_16x16x32_bf16(
                    af[mf], bb[nf], acc[mf][nf], 0, 0, 0);
        __syncthreads();
    }

    // epilogue. C/D layout: col = lane&15, row = (lane>>4)*4 + r  [m89]
    const int orow = (lane >> 4) * 4, ocol = lane & 15;
    if (MODE == 0) {
#pragma unroll
        for (int mf = 0; mf < 4; ++mf)
#pragma unroll
            for (int nf = 0; nf < 4; ++nf)
#pragma unroll
                for (int r = 0; r < 4; ++r) {
                    size_t row = (size_t)(mBlk + wr * 64 + mf * 16 + orow + r);
                    size_t col = (size_t)(pBlk + wc * 64 + nf * 16 + ocol);
                    Cj[row * NN + col] = (bf16_t)acc[mf][nf][r];
                }
    }
    // transpose through LDS -> node-major GT
    const float scale = (MODE == 1) ? 2.f : 1.f;
#pragma unroll
    for (int mf = 0; mf < 4; ++mf)
#pragma unroll
        for (int nf = 0; nf < 4; ++nf)
#pragma unroll
            for (int r = 0; r < 4; ++r) {
                int trow = wr * 64 + mf * 16 + orow + r;   // local j
                int tcol = wc * 64 + nf * 16 + ocol;       // local n
                T[(size_t)tcol * 136 + trow] = (bf16_t)(scale * acc[mf][nf][r]);
            }
    __syncthreads();
    {
        const int row = tid >> 1, half = tid & 1;          // local n, j-half
        const bf16_t* src = T + (size_t)row * 136 + half * 64;
        bf16_t* dst = GT + (size_t)(pBlk + row) * JDIM + mBlk + half * 64;
#pragma unroll
        for (int s = 0; s < 8; ++s)
            *reinterpret_cast<uint4*>(dst + s * 8) =
                *reinterpret_cast<const uint4*>(src + s * 8);
    }
}

// ---------------------------------------------------------------------------
// Final grouped matmul, MFMA. Block = 4 waves, 4 nodes (sequential).
// Per node: out[b,o] = sum_ki g[b][ki] * Wt[n][o][ki] + bias[o]
//   g[b][0:64]    = x[b][n][:]            (fp32 -> bf16)
//   g[b][64:128]  = G1T[n][b*64+:]        (bf16)
//   g[b][128:192] = G2raw[n][b*64+:] - x  (the folded -Y0 term)
// Waves split o (16 cols each); A-frags shared via LDS.
// ---------------------------------------------------------------------------
__global__ __launch_bounds__(256) void gconv_kernel(
    const float* __restrict__ x,   const float* __restrict__ E,
    const float* __restrict__ bp,  const bf16_t* __restrict__ G1T,
    const bf16_t* __restrict__ G2T, const bf16_t* __restrict__ Wt,
    float* __restrict__ out) {
    __shared__ bf16_t g[64][200];          // 25.6 KB, 2-way-conflict-free pad
    const int tid = threadIdx.x, wave = tid >> 6, lane = tid & 63;
    const int lrow = lane & 15, lk = (lane >> 4) * 8;
    const int o = wave * 16 + lrow;        // this lane's output col

    float bpo[EMB];
#pragma unroll
    for (int d = 0; d < EMB; ++d) bpo[d] = bp[d * COUT + o];

    for (int tn = 0; tn < 4; ++tn) {
        const int n = blockIdx.x * 4 + tn;
        // ---- stage g (cooperative, 512 chunks of 8 elems) ----
#pragma unroll
        for (int p = 0; p < 2; ++p) {
            int idx = p * 256 + tid;                 // 0..511
            int b = idx >> 3, ic = (idx & 7) * 8;
            const float4* xs = reinterpret_cast<const float4*>(
                x + ((size_t)b * NN + n) * CIN + ic);
            float4 x0 = xs[0], x1 = xs[1];
            uint4 g1v = *reinterpret_cast<const uint4*>(G1T + (size_t)n * JDIM + idx * 8);
            uint4 g2v = *reinterpret_cast<const uint4*>(G2T + (size_t)n * JDIM + idx * 8);
            float xv[8] = {x0.x, x0.y, x0.z, x0.w, x1.x, x1.y, x1.z, x1.w};
            const bf16_t* g2p = reinterpret_cast<const bf16_t*>(&g2v);
            ushort4 g0b[2], g2b[2];
#pragma unroll
            for (int e = 0; e < 8; ++e) {
                ((unsigned short*)g0b)[e] = bfbits(xv[e]);
                ((unsigned short*)g2b)[e] = bfbits((float)g2p[e] - xv[e]);
            }
            *reinterpret_cast<uint4*>(&g[b][ic])       = *reinterpret_cast<uint4*>(g0b);
            *reinterpret_cast<uint4*>(&g[b][64 + ic])  = g1v;
            *reinterpret_cast<uint4*>(&g[b][128 + ic]) = *reinterpret_cast<uint4*>(g2b);
        }
        __syncthreads();
        // ---- compute: 64x16 output slice per wave, K=192 ----
        f32x4 acc[4] = {};
        const bf16_t* wtn = Wt + (size_t)n * 12288 + (size_t)o * WKI;
#pragma unroll
        for (int ks = 0; ks < 6; ++ks) {
            bf16x8 bb = *reinterpret_cast<const bf16x8*>(wtn + ks * 32 + lk);
#pragma unroll
            for (int mf = 0; mf < 4; ++mf) {
                bf16x8 af = *reinterpret_cast<const bf16x8*>(&g[mf * 16 + lrow][ks * 32 + lk]);
                acc[mf] = __builtin_amdgcn_mfma_f32_16x16x32_bf16(af, bb, acc[mf], 0, 0, 0);
            }
        }
        float bo = 0.f;
        const float* en = E + (size_t)n * EMB;
#pragma unroll
        for (int d = 0; d < EMB; ++d) bo += en[d] * bpo[d];
#pragma unroll
        for (int mf = 0; mf < 4; ++mf)
#pragma unroll
            for (int r = 0; r < 4; ++r) {
                int b = mf * 16 + (lane >> 4) * 4 + r;
                out[((size_t)b * NN + n) * COUT + o] = acc[mf][r] + bo;
            }
        __syncthreads();
    }
}

// ---------------------------------------------------------------------------
extern "C" void kernel_launch(void* const* d_in, const int* in_sizes, int n_in,
                              void* d_out, int out_size, void* d_ws, size_t ws_size,
                              hipStream_t stream) {
    const float* x  = (const float*)d_in[0];   // (64,2048,64)
    const float* E  = (const float*)d_in[1];   // (2048,16)
    const float* wp = (const float*)d_in[2];   // (16,3,64,64)
    const float* bp = (const float*)d_in[3];   // (16,64)
    float* out = (float*)d_out;

    bf16_t* ws = (bf16_t*)d_ws;
    bf16_t* Wt  = ws;                          // 2048*12288      = 48 MB
    bf16_t* Sb  = Wt + (size_t)NN * 12288;     // 2048*2048       =  8 MB
    bf16_t* Y0  = Sb + (size_t)NN * NN;        // 4096*2048       = 16 MB
    bf16_t* Y1  = Y0 + (size_t)JDIM * NN;      // 16 MB
    bf16_t* G1T = Y1 + (size_t)JDIM * NN;      // 16 MB  (total 104 MB)
    bf16_t* G2T = Y0;                          // alias: Y0 dead after gemm<0>

    wgen_kernel<<<dim3(12288 / 512, NN / 128), 256, 0, stream>>>(E, wp, Wt);
    support_kernel<<<NN, 256, 0, stream>>>(E, Sb);
    y0_kernel<<<dim3(NN / 64, BATCH), 256, 0, stream>>>(x, Y0);

    dim3 ggrid(NN / 128, JDIM / 128);          // 16 x 32 = 512 blocks
    gemm_bt<0><<<ggrid, 256, 0, stream>>>(Y0, Sb, Y1, G1T);
    gemm_bt<1><<<ggrid, 256, 0, stream>>>(Y1, Sb, nullptr, G2T);

    gconv_kernel<<<NN / 4, 256, 0, stream>>>(x, E, bp, G1T, G2T, Wt, out);
}